// Round 1
// baseline (58.965 us; speedup 1.0000x reference)
//
#include <hip/hip_runtime.h>

#define EPS 1e-8f

namespace {
constexpr int Bc = 128;
constexpr int Tc = 128;
constexpr int Dc = 512;
constexpr int D4 = Dc / 4;                       // 128 float4 per row
constexpr int THREADS = 256;
constexpr int BLOCKS_PER_TENSOR = (Bc * D4) / THREADS;  // 64
}

// Kernel 1: fmean[q][b][d] = (1/T) * sum_t f_q[b][t][d]   (q = i*3+j)
__global__ __launch_bounds__(256) void hm_mean_kernel(
    const float* __restrict__ f0, const float* __restrict__ f1,
    const float* __restrict__ f2, const float* __restrict__ f3,
    const float* __restrict__ f4, const float* __restrict__ f5,
    const float* __restrict__ f6, const float* __restrict__ f7,
    const float* __restrict__ f8, float* __restrict__ fmean)
{
    const float* fs[9] = {f0, f1, f2, f3, f4, f5, f6, f7, f8};
    const int q   = blockIdx.x / BLOCKS_PER_TENSOR;
    const int idx = (blockIdx.x % BLOCKS_PER_TENSOR) * THREADS + threadIdx.x; // b*D4+d4
    const int b   = idx >> 7;          // /D4
    const int d4  = idx & (D4 - 1);

    const float4* src = reinterpret_cast<const float4*>(fs[q]) + (size_t)b * Tc * D4 + d4;

    float4 a0 = make_float4(0.f, 0.f, 0.f, 0.f);
    float4 a1 = make_float4(0.f, 0.f, 0.f, 0.f);
    #pragma unroll 8
    for (int t = 0; t < Tc; t += 2) {
        float4 v0 = src[(size_t)t * D4];
        float4 v1 = src[(size_t)(t + 1) * D4];
        a0.x += v0.x; a0.y += v0.y; a0.z += v0.z; a0.w += v0.w;
        a1.x += v1.x; a1.y += v1.y; a1.z += v1.z; a1.w += v1.w;
    }
    const float inv = 1.0f / (float)Tc;
    float4 r;
    r.x = (a0.x + a1.x) * inv;
    r.y = (a0.y + a1.y) * inv;
    r.z = (a0.z + a1.z) * inv;
    r.w = (a0.w + a1.w) * inv;
    reinterpret_cast<float4*>(fmean)[(size_t)q * Bc * D4 + idx] = r;
}

// Kernel 2: everything else. One block (256 thr) per batch element b.
__global__ __launch_bounds__(256) void hm_final_kernel(
    const float* __restrict__ joint, const float* __restrict__ fmean,
    float* __restrict__ out)
{
    const int b   = blockIdx.x;
    const int tid = threadIdx.x;
    const int lane = tid & 63;
    const int wave = tid >> 6;

    __shared__ float sm_red[4][9];
    __shared__ float sm_red2[4][3];
    __shared__ float sm_num[9];
    __shared__ float sm_num2[3];

    // each thread handles d = tid and d = tid + 256
    float jd[2];
    float fm[2][9];
    float pnum[9];
    #pragma unroll
    for (int q = 0; q < 9; ++q) pnum[q] = 0.f;

    #pragma unroll
    for (int r = 0; r < 2; ++r) {
        const int d = tid + r * 256;
        jd[r] = joint[(size_t)b * Dc + d];
        #pragma unroll
        for (int q = 0; q < 9; ++q) {
            fm[r][q] = fmean[((size_t)q * Bc + b) * Dc + d];
            pnum[q] += jd[r] * fm[r][q];
        }
    }

    // block-reduce 9 partial dot products -> num[i,j]
    #pragma unroll
    for (int q = 0; q < 9; ++q)
        #pragma unroll
        for (int off = 32; off > 0; off >>= 1)
            pnum[q] += __shfl_down(pnum[q], off, 64);
    if (lane == 0)
        #pragma unroll
        for (int q = 0; q < 9; ++q) sm_red[wave][q] = pnum[q];
    __syncthreads();
    if (tid < 9)
        sm_num[tid] = sm_red[0][tid] + sm_red[1][tid] + sm_red[2][tid] + sm_red[3][tid];
    __syncthreads();

    // b weights
    float num[9];
    #pragma unroll
    for (int q = 0; q < 9; ++q) num[q] = sm_num[q];
    float bw[3][3];
    #pragma unroll
    for (int i = 0; i < 3; ++i) {
        const float denom = num[i * 3] + num[i * 3 + 1] + num[i * 3 + 2] + EPS;
        const float rdenom = 1.0f / denom;
        #pragma unroll
        for (int j = 0; j < 3; ++j) bw[i][j] = num[i * 3 + j] * rdenom;
    }

    // fii_mean per d (in registers) + num2 partials
    float fii[2][3];
    float pnum2[3] = {0.f, 0.f, 0.f};
    #pragma unroll
    for (int r = 0; r < 2; ++r)
        #pragma unroll
        for (int i = 0; i < 3; ++i) {
            fii[r][i] = bw[i][0] * fm[r][i * 3 + 0]
                      + bw[i][1] * fm[r][i * 3 + 1]
                      + bw[i][2] * fm[r][i * 3 + 2];
            pnum2[i] += jd[r] * fii[r][i];
        }

    // block-reduce 3 values -> num2[i]
    #pragma unroll
    for (int i = 0; i < 3; ++i)
        #pragma unroll
        for (int off = 32; off > 0; off >>= 1)
            pnum2[i] += __shfl_down(pnum2[i], off, 64);
    if (lane == 0)
        #pragma unroll
        for (int i = 0; i < 3; ++i) sm_red2[wave][i] = pnum2[i];
    __syncthreads();
    if (tid < 3)
        sm_num2[tid] = sm_red2[0][tid] + sm_red2[1][tid] + sm_red2[2][tid] + sm_red2[3][tid];
    __syncthreads();

    const float denom2 = sm_num2[0] + sm_num2[1] + sm_num2[2] + EPS;
    const float rd2 = 1.0f / denom2;
    float lam[3];
    #pragma unroll
    for (int i = 0; i < 3; ++i) lam[i] = sm_num2[i] * rd2;

    #pragma unroll
    for (int r = 0; r < 2; ++r) {
        const int d = tid + r * 256;
        out[(size_t)b * Dc + d] =
            lam[0] * fii[r][0] + lam[1] * fii[r][1] + lam[2] * fii[r][2];
    }
}

extern "C" void kernel_launch(void* const* d_in, const int* in_sizes, int n_in,
                              void* d_out, int out_size, void* d_ws, size_t ws_size,
                              hipStream_t stream) {
    const float* joint = (const float*)d_in[0];
    const float* f[9];
    for (int q = 0; q < 9; ++q) f[q] = (const float*)d_in[1 + q];
    float* out = (float*)d_out;
    float* fmean = (float*)d_ws;  // 9*B*D floats = 1.18 MB

    const int grid1 = 9 * BLOCKS_PER_TENSOR;  // 576
    hipLaunchKernelGGL(hm_mean_kernel, dim3(grid1), dim3(THREADS), 0, stream,
                       f[0], f[1], f[2], f[3], f[4], f[5], f[6], f[7], f[8], fmean);
    hipLaunchKernelGGL(hm_final_kernel, dim3(Bc), dim3(THREADS), 0, stream,
                       joint, fmean, out);
}